// Round 1
// baseline (565.797 us; speedup 1.0000x reference)
//
#include <hip/hip_runtime.h>

#define N_NODESC 100000
#define N_EDGESC 1600000
// IN_C = 128, HID_C = 128, OUT_C = 64

// ---------------- degree / dinv ----------------
__global__ void k_deg_count(const int* __restrict__ dst, int* __restrict__ deg) {
    int e = blockIdx.x * blockDim.x + threadIdx.x;
    if (e < N_EDGESC) atomicAdd(&deg[dst[e]], 1);
}

__global__ void k_dinv(const int* __restrict__ deg, float* __restrict__ dinv) {
    int n = blockIdx.x * blockDim.x + threadIdx.x;
    if (n < N_NODESC) dinv[n] = rsqrtf((float)deg[n] + 1.0f);
}

// ---------------- exclusive scan over deg (3 kernels) ----------------
#define SCAN_CHUNK 1024

__global__ void k_scan1(const int* __restrict__ deg, int* __restrict__ part) {
    __shared__ int sdata[256];
    int t = threadIdx.x;
    int base = blockIdx.x * SCAN_CHUNK + t * 4;
    int s = 0;
#pragma unroll
    for (int j = 0; j < 4; ++j) { int i = base + j; if (i < N_NODESC) s += deg[i]; }
    sdata[t] = s;
    __syncthreads();
    for (int off = 128; off > 0; off >>= 1) {
        if (t < off) sdata[t] += sdata[t + off];
        __syncthreads();
    }
    if (t == 0) part[blockIdx.x] = sdata[0];
}

__global__ void k_scan2(int* part, int nb) {
    if (threadIdx.x == 0 && blockIdx.x == 0) {
        int run = 0;
        for (int b = 0; b < nb; ++b) { int v = part[b]; part[b] = run; run += v; }
    }
}

__global__ void k_scan3(const int* __restrict__ deg, const int* __restrict__ part,
                        int* __restrict__ row_ptr, int* __restrict__ cursor) {
    __shared__ int sdata[256];
    int t = threadIdx.x;
    int base = blockIdx.x * SCAN_CHUNK + t * 4;
    int v[4];
    int s = 0;
#pragma unroll
    for (int j = 0; j < 4; ++j) { int i = base + j; v[j] = (i < N_NODESC) ? deg[i] : 0; s += v[j]; }
    sdata[t] = s;
    __syncthreads();
    int own = s;
    for (int off = 1; off < 256; off <<= 1) {
        int add = (t >= off) ? sdata[t - off] : 0;
        __syncthreads();
        sdata[t] += add;
        __syncthreads();
    }
    int excl = sdata[t] - own + part[blockIdx.x];
#pragma unroll
    for (int j = 0; j < 4; ++j) {
        int i = base + j;
        if (i < N_NODESC) { row_ptr[i] = excl; cursor[i] = excl; excl += v[j]; }
    }
}

// ---------------- CSR fill: {src, norm} per edge, sorted by dst ----------------
__global__ void k_fill(const int* __restrict__ src, const int* __restrict__ dst,
                       const float* __restrict__ dinv, int* __restrict__ cursor,
                       int2* __restrict__ sw) {
    int e = blockIdx.x * blockDim.x + threadIdx.x;
    if (e >= N_EDGESC) return;
    int s = src[e], d = dst[e];
    int pos = atomicAdd(&cursor[d], 1);
    int2 r; r.x = s; r.y = __float_as_int(dinv[s] * dinv[d]);
    sw[pos] = r;
}

// ---------------- GEMM: H[N,NOUT] = X[N,128] @ W[128,NOUT] ----------------
// 32 nodes/block, 8 nodes/wave (half-wave owns 4 nodes), lane&31 owns NOUT/32 cols.
// K staged in 4 chunks of 32: x transposed into LDS (pitch 36 to keep 16B align),
// W chunk flat in LDS. Inner k: 2 LDS vector reads + 16 (or 8) FMAs.
__global__ __launch_bounds__(256) void k_gemm128(const float* __restrict__ X,
                                                 const float* __restrict__ Wg,
                                                 float* __restrict__ H) {
    __shared__ __align__(16) float xt[32][36];
    __shared__ __align__(16) float wl[32 * 128];
    int t = threadIdx.x;
    int w = t >> 6, lane = t & 63, l32 = lane & 31, half = lane >> 5;
    int nodeBase = blockIdx.x * 32;
    int nl = t >> 3;   // staging: node 0..31
    int q  = t & 7;    // staging: k-quad 0..7
    const float4* Wg4 = (const float4*)Wg;
    float4* wl4 = (float4*)wl;
    float4 a0 = {0,0,0,0}, a1 = {0,0,0,0}, a2 = {0,0,0,0}, a3 = {0,0,0,0};
    for (int kc = 0; kc < 4; ++kc) {
        float4 xv = *(const float4*)&X[(size_t)(nodeBase + nl) * 128 + kc * 32 + q * 4];
        xt[q * 4 + 0][nl] = xv.x; xt[q * 4 + 1][nl] = xv.y;
        xt[q * 4 + 2][nl] = xv.z; xt[q * 4 + 3][nl] = xv.w;
#pragma unroll
        for (int r = 0; r < 4; ++r) wl4[r * 256 + t] = Wg4[kc * 1024 + r * 256 + t];
        __syncthreads();
#pragma unroll
        for (int kk = 0; kk < 32; ++kk) {
            float4 xq = *(const float4*)&xt[kk][w * 8 + half * 4];
            float4 wv = *(const float4*)&wl[kk * 128 + l32 * 4];
            a0.x += xq.x * wv.x; a0.y += xq.x * wv.y; a0.z += xq.x * wv.z; a0.w += xq.x * wv.w;
            a1.x += xq.y * wv.x; a1.y += xq.y * wv.y; a1.z += xq.y * wv.z; a1.w += xq.y * wv.w;
            a2.x += xq.z * wv.x; a2.y += xq.z * wv.y; a2.z += xq.z * wv.z; a2.w += xq.z * wv.w;
            a3.x += xq.w * wv.x; a3.y += xq.w * wv.y; a3.z += xq.w * wv.z; a3.w += xq.w * wv.w;
        }
        __syncthreads();
    }
    int n0 = nodeBase + w * 8 + half * 4;
    *(float4*)&H[(size_t)(n0 + 0) * 128 + l32 * 4] = a0;
    *(float4*)&H[(size_t)(n0 + 1) * 128 + l32 * 4] = a1;
    *(float4*)&H[(size_t)(n0 + 2) * 128 + l32 * 4] = a2;
    *(float4*)&H[(size_t)(n0 + 3) * 128 + l32 * 4] = a3;
}

__global__ __launch_bounds__(256) void k_gemm64(const float* __restrict__ X,
                                                const float* __restrict__ Wg,
                                                float* __restrict__ H) {
    __shared__ __align__(16) float xt[32][36];
    __shared__ __align__(16) float wl[32 * 64];
    int t = threadIdx.x;
    int w = t >> 6, lane = t & 63, l32 = lane & 31, half = lane >> 5;
    int nodeBase = blockIdx.x * 32;
    int nl = t >> 3;
    int q  = t & 7;
    const float4* Wg4 = (const float4*)Wg;
    float4* wl4 = (float4*)wl;
    float2 a0 = {0,0}, a1 = {0,0}, a2 = {0,0}, a3 = {0,0};
    for (int kc = 0; kc < 4; ++kc) {
        float4 xv = *(const float4*)&X[(size_t)(nodeBase + nl) * 128 + kc * 32 + q * 4];
        xt[q * 4 + 0][nl] = xv.x; xt[q * 4 + 1][nl] = xv.y;
        xt[q * 4 + 2][nl] = xv.z; xt[q * 4 + 3][nl] = xv.w;
#pragma unroll
        for (int r = 0; r < 2; ++r) wl4[r * 256 + t] = Wg4[kc * 512 + r * 256 + t];
        __syncthreads();
#pragma unroll
        for (int kk = 0; kk < 32; ++kk) {
            float4 xq = *(const float4*)&xt[kk][w * 8 + half * 4];
            float2 wv = *(const float2*)&wl[kk * 64 + l32 * 2];
            a0.x += xq.x * wv.x; a0.y += xq.x * wv.y;
            a1.x += xq.y * wv.x; a1.y += xq.y * wv.y;
            a2.x += xq.z * wv.x; a2.y += xq.z * wv.y;
            a3.x += xq.w * wv.x; a3.y += xq.w * wv.y;
        }
        __syncthreads();
    }
    int n0 = nodeBase + w * 8 + half * 4;
    *(float2*)&H[(size_t)(n0 + 0) * 64 + l32 * 2] = a0;
    *(float2*)&H[(size_t)(n0 + 1) * 64 + l32 * 2] = a1;
    *(float2*)&H[(size_t)(n0 + 2) * 64 + l32 * 2] = a2;
    *(float2*)&H[(size_t)(n0 + 3) * 64 + l32 * 2] = a3;
}

// ---------------- aggregation: out = sum_{e->n} h[src]*w + h[n]*dinv^2 + b (opt relu) --
__global__ __launch_bounds__(256) void k_agg128(const float* __restrict__ H,
        const int2* __restrict__ sw, const int* __restrict__ row_ptr,
        const int* __restrict__ deg, const float* __restrict__ dinv,
        const float* __restrict__ bias, float* __restrict__ out) {
    int g = blockIdx.x * 8 + (threadIdx.x >> 5);  // node (half-wave per node)
    int l = threadIdx.x & 31;
    int start = row_ptr[g];
    int cnt = deg[g];
    float4 acc = {0, 0, 0, 0};
    for (int j = 0; j < cnt; ++j) {
        int2 e = sw[start + j];
        float wgt = __int_as_float(e.y);
        float4 hv = *(const float4*)&H[(size_t)e.x * 128 + l * 4];
        acc.x += hv.x * wgt; acc.y += hv.y * wgt;
        acc.z += hv.z * wgt; acc.w += hv.w * wgt;
    }
    float dv = dinv[g];
    float dv2 = dv * dv;
    float4 hs = *(const float4*)&H[(size_t)g * 128 + l * 4];
    float4 bv = *(const float4*)&bias[l * 4];
    acc.x += hs.x * dv2 + bv.x; acc.y += hs.y * dv2 + bv.y;
    acc.z += hs.z * dv2 + bv.z; acc.w += hs.w * dv2 + bv.w;
    acc.x = fmaxf(acc.x, 0.f); acc.y = fmaxf(acc.y, 0.f);
    acc.z = fmaxf(acc.z, 0.f); acc.w = fmaxf(acc.w, 0.f);
    *(float4*)&out[(size_t)g * 128 + l * 4] = acc;
}

__global__ __launch_bounds__(256) void k_agg64(const float* __restrict__ H,
        const int2* __restrict__ sw, const int* __restrict__ row_ptr,
        const int* __restrict__ deg, const float* __restrict__ dinv,
        const float* __restrict__ bias, float* __restrict__ out) {
    int g = blockIdx.x * 8 + (threadIdx.x >> 5);
    int l = threadIdx.x & 31;
    int start = row_ptr[g];
    int cnt = deg[g];
    float2 acc = {0, 0};
    for (int j = 0; j < cnt; ++j) {
        int2 e = sw[start + j];
        float wgt = __int_as_float(e.y);
        float2 hv = *(const float2*)&H[(size_t)e.x * 64 + l * 2];
        acc.x += hv.x * wgt; acc.y += hv.y * wgt;
    }
    float dv = dinv[g];
    float dv2 = dv * dv;
    float2 hs = *(const float2*)&H[(size_t)g * 64 + l * 2];
    float2 bv = *(const float2*)&bias[l * 2];
    acc.x += hs.x * dv2 + bv.x;
    acc.y += hs.y * dv2 + bv.y;
    *(float2*)&out[(size_t)g * 64 + l * 2] = acc;
}

extern "C" void kernel_launch(void* const* d_in, const int* in_sizes, int n_in,
                              void* d_out, int out_size, void* d_ws, size_t ws_size,
                              hipStream_t stream) {
    const float* x  = (const float*)d_in[0];
    const int*   ei = (const int*)d_in[1];
    const float* W1 = (const float*)d_in[2];
    const float* b1 = (const float*)d_in[3];
    const float* W2 = (const float*)d_in[4];
    const float* b2 = (const float*)d_in[5];
    float* out = (float*)d_out;
    const int* src = ei;
    const int* dst = ei + N_EDGESC;

    char* ws = (char*)d_ws;
    size_t off = 0;
    auto alloc = [&](size_t bytes) -> void* {
        off = (off + 255) & ~(size_t)255;
        void* p = ws + off;
        off += bytes;
        return p;
    };
    int*   deg     = (int*)  alloc((size_t)N_NODESC * 4);
    float* dinv    = (float*)alloc((size_t)N_NODESC * 4);
    int*   row_ptr = (int*)  alloc((size_t)N_NODESC * 4);
    int*   cursor  = (int*)  alloc((size_t)N_NODESC * 4);
    int*   part    = (int*)  alloc(128 * 4);
    int2*  sw      = (int2*) alloc((size_t)N_EDGESC * 8);
    float* h1      = (float*)alloc((size_t)N_NODESC * 128 * 4);
    float* h       = (float*)alloc((size_t)N_NODESC * 128 * 4);
    float* h2      = h1;  // h1 dead after k_agg128; reuse for layer-2 GEMM output

    const int nbScan = (N_NODESC + SCAN_CHUNK - 1) / SCAN_CHUNK;  // 98

    hipMemsetAsync(deg, 0, (size_t)N_NODESC * 4, stream);
    k_deg_count<<<N_EDGESC / 256, 256, 0, stream>>>(dst, deg);
    k_dinv<<<(N_NODESC + 255) / 256, 256, 0, stream>>>(deg, dinv);
    k_scan1<<<nbScan, 256, 0, stream>>>(deg, part);
    k_scan2<<<1, 64, 0, stream>>>(part, nbScan);
    k_scan3<<<nbScan, 256, 0, stream>>>(deg, part, row_ptr, cursor);
    k_fill<<<N_EDGESC / 256, 256, 0, stream>>>(src, dst, dinv, cursor, sw);

    k_gemm128<<<N_NODESC / 32, 256, 0, stream>>>(x, W1, h1);                 // h1 = x@W1
    k_agg128<<<N_NODESC / 8, 256, 0, stream>>>(h1, sw, row_ptr, deg, dinv, b1, h);  // h = relu(A*h1+b1)
    k_gemm64<<<N_NODESC / 32, 256, 0, stream>>>(h, W2, h2);                  // h2 = h@W2
    k_agg64<<<N_NODESC / 8, 256, 0, stream>>>(h2, sw, row_ptr, deg, dinv, b2, out); // out = A*h2+b2
}

// Round 2
// 488.098 us; speedup vs baseline: 1.1592x; 1.1592x over previous
//
#include <hip/hip_runtime.h>

#define N_NODESC 100000
#define N_EDGESC 1600000
// IN_C = 128, HID_C = 128, OUT_C = 64

typedef __attribute__((ext_vector_type(4))) float floatx4;
typedef __attribute__((ext_vector_type(8))) short shortx8;

// ---------------- bf16 split helpers ----------------
__device__ __forceinline__ unsigned short f32_to_bf16_rne(float f) {
    unsigned int u = __float_as_uint(f);
    unsigned int r = u + 0x7fffu + ((u >> 16) & 1u);
    return (unsigned short)(r >> 16);
}
__device__ __forceinline__ float bf16_to_f32(unsigned short h) {
    return __uint_as_float(((unsigned int)h) << 16);
}

// ---------------- degree / dinv ----------------
__global__ void k_deg_count(const int* __restrict__ dst, int* __restrict__ deg) {
    int e = blockIdx.x * blockDim.x + threadIdx.x;
    if (e < N_EDGESC) atomicAdd(&deg[dst[e]], 1);
}

__global__ void k_dinv(const int* __restrict__ deg, float* __restrict__ dinv) {
    int n = blockIdx.x * blockDim.x + threadIdx.x;
    if (n < N_NODESC) dinv[n] = rsqrtf((float)deg[n] + 1.0f);
}

// ---------------- exclusive scan over deg (3 kernels) ----------------
#define SCAN_CHUNK 1024

__global__ void k_scan1(const int* __restrict__ deg, int* __restrict__ part) {
    __shared__ int sdata[256];
    int t = threadIdx.x;
    int base = blockIdx.x * SCAN_CHUNK + t * 4;
    int s = 0;
#pragma unroll
    for (int j = 0; j < 4; ++j) { int i = base + j; if (i < N_NODESC) s += deg[i]; }
    sdata[t] = s;
    __syncthreads();
    for (int off = 128; off > 0; off >>= 1) {
        if (t < off) sdata[t] += sdata[t + off];
        __syncthreads();
    }
    if (t == 0) part[blockIdx.x] = sdata[0];
}

__global__ void k_scan2(int* part, int nb) {
    if (threadIdx.x == 0 && blockIdx.x == 0) {
        int run = 0;
        for (int b = 0; b < nb; ++b) { int v = part[b]; part[b] = run; run += v; }
    }
}

__global__ void k_scan3(const int* __restrict__ deg, const int* __restrict__ part,
                        int* __restrict__ row_ptr, int* __restrict__ cursor) {
    __shared__ int sdata[256];
    int t = threadIdx.x;
    int base = blockIdx.x * SCAN_CHUNK + t * 4;
    int v[4];
    int s = 0;
#pragma unroll
    for (int j = 0; j < 4; ++j) { int i = base + j; v[j] = (i < N_NODESC) ? deg[i] : 0; s += v[j]; }
    sdata[t] = s;
    __syncthreads();
    int own = s;
    for (int off = 1; off < 256; off <<= 1) {
        int add = (t >= off) ? sdata[t - off] : 0;
        __syncthreads();
        sdata[t] += add;
        __syncthreads();
    }
    int excl = sdata[t] - own + part[blockIdx.x];
#pragma unroll
    for (int j = 0; j < 4; ++j) {
        int i = base + j;
        if (i < N_NODESC) { row_ptr[i] = excl; cursor[i] = excl; excl += v[j]; }
    }
}

// ---------------- CSR fill: {src, norm} per edge, sorted by dst ----------------
__global__ void k_fill(const int* __restrict__ src, const int* __restrict__ dst,
                       const float* __restrict__ dinv, int* __restrict__ cursor,
                       int2* __restrict__ sw) {
    int e = blockIdx.x * blockDim.x + threadIdx.x;
    if (e >= N_EDGESC) return;
    int s = src[e], d = dst[e];
    int pos = atomicAdd(&cursor[d], 1);
    int2 r; r.x = s; r.y = __float_as_int(dinv[s] * dinv[d]);
    sw[pos] = r;
}

// ---------------- W fragment pre-pack: fp32 [128][NOUT] -> bf16 hi/lo frag order --
// frag element offset: (((kc*C + c)*4 + q)*16 + n)*8 + j  (k = kc*32+q*8+j, col = c*16+n)
// -> lane l of a wave loads 16 contiguous bytes at ((kc*C + c)*64 + l)*8 elems.
template<int NOUT>
__global__ void k_wfrag(const float* __restrict__ W,
                        unsigned short* __restrict__ whi, unsigned short* __restrict__ wlo) {
    int idx = blockIdx.x * 256 + threadIdx.x;    // idx = k*NOUT + col
    constexpr int C = NOUT / 16;
    int k = idx / NOUT, col = idx % NOUT;
    float f = W[idx];
    unsigned short hi = f32_to_bf16_rne(f);
    unsigned short lo = f32_to_bf16_rne(f - bf16_to_f32(hi));
    int kc = k >> 5, q = (k >> 3) & 3, j = k & 7;
    int c = col >> 4, n = col & 15;
    int o = (((kc * C + c) * 4 + q) * 16 + n) * 8 + j;
    whi[o] = hi; wlo[o] = lo;
}

// ---------------- GEMM via MFMA bf16x3: H[N,NOUT] = X[N,128] @ W ----------------
// Block 256 = 4 waves; wave owns 32 rows (two 16-row m-tiles) x all NOUT cols.
// Per kc (K-chunk of 32): convert A rows to bf16 hi/lo frags in-register, then
// for each 16-col tile load B hi/lo frags (coalesced dwordx4 from packed global,
// L2-resident) and issue 3 MFMAs per (m,c): hi*hi + lo*hi + hi*lo.
template<int NOUT>
__global__ __launch_bounds__(256) void k_gemm_mfma(const float* __restrict__ X,
        const unsigned short* __restrict__ whi, const unsigned short* __restrict__ wlo,
        float* __restrict__ H) {
    constexpr int C = NOUT / 16;
    int wv = threadIdx.x >> 6, lane = threadIdx.x & 63;
    int n16 = lane & 15, q = lane >> 4;
    int rowBase = blockIdx.x * 128 + wv * 32;
    floatx4 acc[2][C];
#pragma unroll
    for (int m = 0; m < 2; ++m)
#pragma unroll
        for (int c = 0; c < C; ++c) acc[m][c] = (floatx4){0.f, 0.f, 0.f, 0.f};

    const shortx8* whi8 = (const shortx8*)whi;
    const shortx8* wlo8 = (const shortx8*)wlo;

    for (int kc = 0; kc < 4; ++kc) {
        shortx8 ahi[2], alo[2];
#pragma unroll
        for (int m = 0; m < 2; ++m) {
            int r = rowBase + m * 16 + n16;
            if (r >= N_NODESC) r = N_NODESC - 1;
            const float* xp = &X[(size_t)r * 128 + kc * 32 + q * 8];
            floatx4 x0 = *(const floatx4*)xp;
            floatx4 x1 = *(const floatx4*)(xp + 4);
#pragma unroll
            for (int jj = 0; jj < 4; ++jj) {
                unsigned short h0 = f32_to_bf16_rne(x0[jj]);
                ahi[m][jj] = (short)h0;
                alo[m][jj] = (short)f32_to_bf16_rne(x0[jj] - bf16_to_f32(h0));
                unsigned short h1 = f32_to_bf16_rne(x1[jj]);
                ahi[m][jj + 4] = (short)h1;
                alo[m][jj + 4] = (short)f32_to_bf16_rne(x1[jj] - bf16_to_f32(h1));
            }
        }
#pragma unroll
        for (int c = 0; c < C; ++c) {
            int fo = (kc * C + c) * 64 + lane;
            shortx8 bhi = whi8[fo];
            shortx8 blo = wlo8[fo];
#pragma unroll
            for (int m = 0; m < 2; ++m) {
                acc[m][c] = __builtin_amdgcn_mfma_f32_16x16x32_bf16(ahi[m], bhi, acc[m][c], 0, 0, 0);
                acc[m][c] = __builtin_amdgcn_mfma_f32_16x16x32_bf16(alo[m], bhi, acc[m][c], 0, 0, 0);
                acc[m][c] = __builtin_amdgcn_mfma_f32_16x16x32_bf16(ahi[m], blo, acc[m][c], 0, 0, 0);
            }
        }
    }
    // C/D: col = c*16 + n16, row = rowBase + m*16 + q*4 + reg
#pragma unroll
    for (int m = 0; m < 2; ++m) {
        int r0 = rowBase + m * 16 + q * 4;
#pragma unroll
        for (int reg = 0; reg < 4; ++reg) {
            int r = r0 + reg;
            if (r < N_NODESC) {
#pragma unroll
                for (int c = 0; c < C; ++c)
                    H[(size_t)r * NOUT + c * 16 + n16] = acc[m][c][reg];
            }
        }
    }
}

// ---------------- aggregation d=128: wave per node, halves = 2 parallel edge streams,
// unroll 2 -> 4 gathers in flight. out = sum h[src]*w + h[n]*dinv^2 + b (+relu) ----
__global__ __launch_bounds__(256) void k_agg128(const float* __restrict__ H,
        const int2* __restrict__ sw, const int* __restrict__ row_ptr,
        const int* __restrict__ deg, const float* __restrict__ dinv,
        const float* __restrict__ bias, float* __restrict__ out) {
    int node = blockIdx.x * 4 + (threadIdx.x >> 6);
    int lane = threadIdx.x & 63;
    int half = lane >> 5, l32 = lane & 31;
    int start = row_ptr[node];
    int end = start + deg[node];
    float4 acc = {0.f, 0.f, 0.f, 0.f};
    int j = start + half;
    for (; j + 2 < end; j += 4) {
        int2 e0 = sw[j];
        int2 e1 = sw[j + 2];
        float4 hv0 = *(const float4*)&H[(size_t)e0.x * 128 + l32 * 4];
        float4 hv1 = *(const float4*)&H[(size_t)e1.x * 128 + l32 * 4];
        float w0 = __int_as_float(e0.y), w1 = __int_as_float(e1.y);
        acc.x += hv0.x * w0 + hv1.x * w1;
        acc.y += hv0.y * w0 + hv1.y * w1;
        acc.z += hv0.z * w0 + hv1.z * w1;
        acc.w += hv0.w * w0 + hv1.w * w1;
    }
    if (j < end) {
        int2 e0 = sw[j];
        float4 hv0 = *(const float4*)&H[(size_t)e0.x * 128 + l32 * 4];
        float w0 = __int_as_float(e0.y);
        acc.x += hv0.x * w0; acc.y += hv0.y * w0;
        acc.z += hv0.z * w0; acc.w += hv0.w * w0;
    }
    acc.x += __shfl_xor(acc.x, 32);
    acc.y += __shfl_xor(acc.y, 32);
    acc.z += __shfl_xor(acc.z, 32);
    acc.w += __shfl_xor(acc.w, 32);
    if (half == 0) {
        float dv = dinv[node];
        float dv2 = dv * dv;
        float4 hs = *(const float4*)&H[(size_t)node * 128 + l32 * 4];
        float4 bv = *(const float4*)&bias[l32 * 4];
        acc.x = fmaxf(acc.x + hs.x * dv2 + bv.x, 0.f);
        acc.y = fmaxf(acc.y + hs.y * dv2 + bv.y, 0.f);
        acc.z = fmaxf(acc.z + hs.z * dv2 + bv.z, 0.f);
        acc.w = fmaxf(acc.w + hs.w * dv2 + bv.w, 0.f);
        *(float4*)&out[(size_t)node * 128 + l32 * 4] = acc;
    }
}

// ---------------- aggregation d=64: wave per node, 4 groups of 16 lanes (float4),
// unroll 2 -> 8 gathers in flight. no relu. ----------------
__global__ __launch_bounds__(256) void k_agg64(const float* __restrict__ H,
        const int2* __restrict__ sw, const int* __restrict__ row_ptr,
        const int* __restrict__ deg, const float* __restrict__ dinv,
        const float* __restrict__ bias, float* __restrict__ out) {
    int node = blockIdx.x * 4 + (threadIdx.x >> 6);
    int lane = threadIdx.x & 63;
    int g = lane >> 4, l16 = lane & 15;
    int start = row_ptr[node];
    int end = start + deg[node];
    float4 acc = {0.f, 0.f, 0.f, 0.f};
    int j = start + g;
    for (; j + 4 < end; j += 8) {
        int2 e0 = sw[j];
        int2 e1 = sw[j + 4];
        float4 hv0 = *(const float4*)&H[(size_t)e0.x * 64 + l16 * 4];
        float4 hv1 = *(const float4*)&H[(size_t)e1.x * 64 + l16 * 4];
        float w0 = __int_as_float(e0.y), w1 = __int_as_float(e1.y);
        acc.x += hv0.x * w0 + hv1.x * w1;
        acc.y += hv0.y * w0 + hv1.y * w1;
        acc.z += hv0.z * w0 + hv1.z * w1;
        acc.w += hv0.w * w0 + hv1.w * w1;
    }
    if (j < end) {
        int2 e0 = sw[j];
        float4 hv0 = *(const float4*)&H[(size_t)e0.x * 64 + l16 * 4];
        float w0 = __int_as_float(e0.y);
        acc.x += hv0.x * w0; acc.y += hv0.y * w0;
        acc.z += hv0.z * w0; acc.w += hv0.w * w0;
    }
    acc.x += __shfl_xor(acc.x, 16); acc.y += __shfl_xor(acc.y, 16);
    acc.z += __shfl_xor(acc.z, 16); acc.w += __shfl_xor(acc.w, 16);
    acc.x += __shfl_xor(acc.x, 32); acc.y += __shfl_xor(acc.y, 32);
    acc.z += __shfl_xor(acc.z, 32); acc.w += __shfl_xor(acc.w, 32);
    if (g == 0) {
        float dv = dinv[node];
        float dv2 = dv * dv;
        float4 hs = *(const float4*)&H[(size_t)node * 64 + l16 * 4];
        float4 bv = *(const float4*)&bias[l16 * 4];
        acc.x += hs.x * dv2 + bv.x;
        acc.y += hs.y * dv2 + bv.y;
        acc.z += hs.z * dv2 + bv.z;
        acc.w += hs.w * dv2 + bv.w;
        *(float4*)&out[(size_t)node * 64 + l16 * 4] = acc;
    }
}

extern "C" void kernel_launch(void* const* d_in, const int* in_sizes, int n_in,
                              void* d_out, int out_size, void* d_ws, size_t ws_size,
                              hipStream_t stream) {
    const float* x  = (const float*)d_in[0];
    const int*   ei = (const int*)d_in[1];
    const float* W1 = (const float*)d_in[2];
    const float* b1 = (const float*)d_in[3];
    const float* W2 = (const float*)d_in[4];
    const float* b2 = (const float*)d_in[5];
    float* out = (float*)d_out;
    const int* src = ei;
    const int* dst = ei + N_EDGESC;

    char* ws = (char*)d_ws;
    size_t off = 0;
    auto alloc = [&](size_t bytes) -> void* {
        off = (off + 255) & ~(size_t)255;
        void* p = ws + off;
        off += bytes;
        return p;
    };
    int*   deg     = (int*)  alloc((size_t)N_NODESC * 4);
    float* dinv    = (float*)alloc((size_t)N_NODESC * 4);
    int*   row_ptr = (int*)  alloc((size_t)N_NODESC * 4);
    int*   cursor  = (int*)  alloc((size_t)N_NODESC * 4);
    int*   part    = (int*)  alloc(128 * 4);
    int2*  sw      = (int2*) alloc((size_t)N_EDGESC * 8);
    unsigned short* w1hi = (unsigned short*)alloc(128 * 128 * 2);
    unsigned short* w1lo = (unsigned short*)alloc(128 * 128 * 2);
    unsigned short* w2hi = (unsigned short*)alloc(128 * 64 * 2);
    unsigned short* w2lo = (unsigned short*)alloc(128 * 64 * 2);
    float* h1      = (float*)alloc((size_t)N_NODESC * 128 * 4);
    float* h       = (float*)alloc((size_t)N_NODESC * 128 * 4);
    float* h2      = h1;  // h1 dead after k_agg128; reuse for layer-2 GEMM output

    const int nbScan = (N_NODESC + SCAN_CHUNK - 1) / SCAN_CHUNK;  // 98
    const int nbGemm = (N_NODESC + 127) / 128;                    // 782

    hipMemsetAsync(deg, 0, (size_t)N_NODESC * 4, stream);
    k_deg_count<<<N_EDGESC / 256, 256, 0, stream>>>(dst, deg);
    k_dinv<<<(N_NODESC + 255) / 256, 256, 0, stream>>>(deg, dinv);
    k_scan1<<<nbScan, 256, 0, stream>>>(deg, part);
    k_scan2<<<1, 64, 0, stream>>>(part, nbScan);
    k_scan3<<<nbScan, 256, 0, stream>>>(deg, part, row_ptr, cursor);
    k_fill<<<N_EDGESC / 256, 256, 0, stream>>>(src, dst, dinv, cursor, sw);

    k_wfrag<128><<<(128 * 128) / 256, 256, 0, stream>>>(W1, w1hi, w1lo);
    k_wfrag<64><<<(128 * 64) / 256, 256, 0, stream>>>(W2, w2hi, w2lo);

    k_gemm_mfma<128><<<nbGemm, 256, 0, stream>>>(x, w1hi, w1lo, h1);
    k_agg128<<<N_NODESC / 4, 256, 0, stream>>>(h1, sw, row_ptr, deg, dinv, b1, h);
    k_gemm_mfma<64><<<nbGemm, 256, 0, stream>>>(h, w2hi, w2lo, h2);
    k_agg64<<<N_NODESC / 4, 256, 0, stream>>>(h2, sw, row_ptr, deg, dinv, b2, out);
}

// Round 3
// 426.081 us; speedup vs baseline: 1.3279x; 1.1456x over previous
//
#include <hip/hip_runtime.h>

#define N_NODESC 100000
#define N_EDGESC 1600000
// IN_C = 128, HID_C = 128, OUT_C = 64

typedef __attribute__((ext_vector_type(4))) float floatx4;
typedef __attribute__((ext_vector_type(8))) short shortx8;

// ---------------- bf16 helpers ----------------
__device__ __forceinline__ unsigned short f32_to_bf16_rne(float f) {
    unsigned int u = __float_as_uint(f);
    unsigned int r = u + 0x7fffu + ((u >> 16) & 1u);
    return (unsigned short)(r >> 16);
}
__device__ __forceinline__ float bf16_to_f32(unsigned short h) {
    return __uint_as_float(((unsigned int)h) << 16);
}
__device__ __forceinline__ float bflo(unsigned int u) { return __uint_as_float(u << 16); }
__device__ __forceinline__ float bfhi(unsigned int u) { return __uint_as_float(u & 0xffff0000u); }
__device__ __forceinline__ unsigned int pack2bf(float a, float b) {
    return ((unsigned int)f32_to_bf16_rne(b) << 16) | (unsigned int)f32_to_bf16_rne(a);
}

// ---------------- degree / dinv ----------------
__global__ void k_deg_count(const int* __restrict__ dst, int* __restrict__ deg) {
    int e = blockIdx.x * blockDim.x + threadIdx.x;
    if (e < N_EDGESC) atomicAdd(&deg[dst[e]], 1);
}

__global__ void k_dinv(const int* __restrict__ deg, float* __restrict__ dinv) {
    int n = blockIdx.x * blockDim.x + threadIdx.x;
    if (n < N_NODESC) dinv[n] = rsqrtf((float)deg[n] + 1.0f);
}

// ---------------- exclusive scan over deg (3 kernels) ----------------
#define SCAN_CHUNK 1024

__global__ void k_scan1(const int* __restrict__ deg, int* __restrict__ part) {
    __shared__ int sdata[256];
    int t = threadIdx.x;
    int base = blockIdx.x * SCAN_CHUNK + t * 4;
    int s = 0;
#pragma unroll
    for (int j = 0; j < 4; ++j) { int i = base + j; if (i < N_NODESC) s += deg[i]; }
    sdata[t] = s;
    __syncthreads();
    for (int off = 128; off > 0; off >>= 1) {
        if (t < off) sdata[t] += sdata[t + off];
        __syncthreads();
    }
    if (t == 0) part[blockIdx.x] = sdata[0];
}

__global__ void k_scan2(int* part, int nb) {
    if (threadIdx.x == 0 && blockIdx.x == 0) {
        int run = 0;
        for (int b = 0; b < nb; ++b) { int v = part[b]; part[b] = run; run += v; }
    }
}

__global__ void k_scan3(const int* __restrict__ deg, const int* __restrict__ part,
                        int* __restrict__ row_ptr, int* __restrict__ cursor) {
    __shared__ int sdata[256];
    int t = threadIdx.x;
    int base = blockIdx.x * SCAN_CHUNK + t * 4;
    int v[4];
    int s = 0;
#pragma unroll
    for (int j = 0; j < 4; ++j) { int i = base + j; v[j] = (i < N_NODESC) ? deg[i] : 0; s += v[j]; }
    sdata[t] = s;
    __syncthreads();
    int own = s;
    for (int off = 1; off < 256; off <<= 1) {
        int add = (t >= off) ? sdata[t - off] : 0;
        __syncthreads();
        sdata[t] += add;
        __syncthreads();
    }
    int excl = sdata[t] - own + part[blockIdx.x];
#pragma unroll
    for (int j = 0; j < 4; ++j) {
        int i = base + j;
        if (i < N_NODESC) { row_ptr[i] = excl; cursor[i] = excl; excl += v[j]; }
    }
}

// ---------------- CSR fill: {src, norm} per edge, sorted by dst ----------------
__global__ void k_fill(const int* __restrict__ src, const int* __restrict__ dst,
                       const float* __restrict__ dinv, int* __restrict__ cursor,
                       int2* __restrict__ sw) {
    int e = blockIdx.x * blockDim.x + threadIdx.x;
    if (e >= N_EDGESC) return;
    int s = src[e], d = dst[e];
    int pos = atomicAdd(&cursor[d], 1);
    int2 r; r.x = s; r.y = __float_as_int(dinv[s] * dinv[d]);
    sw[pos] = r;
}

// ---------------- W fragment pre-pack: fp32 [128][NOUT] -> bf16 hi/lo frag order --
template<int NOUT>
__global__ void k_wfrag(const float* __restrict__ W,
                        unsigned short* __restrict__ whi, unsigned short* __restrict__ wlo) {
    int idx = blockIdx.x * 256 + threadIdx.x;    // idx = k*NOUT + col
    constexpr int C = NOUT / 16;
    int k = idx / NOUT, col = idx % NOUT;
    float f = W[idx];
    unsigned short hi = f32_to_bf16_rne(f);
    unsigned short lo = f32_to_bf16_rne(f - bf16_to_f32(hi));
    int kc = k >> 5, q = (k >> 3) & 3, j = k & 7;
    int c = col >> 4, n = col & 15;
    int o = (((kc * C + c) * 4 + q) * 16 + n) * 8 + j;
    whi[o] = hi; wlo[o] = lo;
}

// ---------------- GEMM via MFMA: H[N,NOUT](bf16) = A[N,128] @ W ----------------
// AFP32=1: A fp32 -> in-register hi/lo split, 3 MFMAs/tile.
// AFP32=0: A bf16 (stored), 2 MFMAs/tile (hi/lo of B only).
// Epilogue: acc -> LDS (fp32, padded pitch) -> coalesced bf16 stores.
template<int NOUT, int AFP32>
__global__ __launch_bounds__(256) void k_gemm_mfma(const void* __restrict__ Xv,
        const unsigned short* __restrict__ whi, const unsigned short* __restrict__ wlo,
        unsigned short* __restrict__ H) {
    constexpr int C = NOUT / 16;
    constexpr int PITCH = NOUT + 4;
    __shared__ __align__(16) float etile[4][16][PITCH];
    int wv = threadIdx.x >> 6, lane = threadIdx.x & 63;
    int n16 = lane & 15, q = lane >> 4;
    int rowBase = blockIdx.x * 128 + wv * 32;
    floatx4 acc[2][C];
#pragma unroll
    for (int m = 0; m < 2; ++m)
#pragma unroll
        for (int c = 0; c < C; ++c) acc[m][c] = (floatx4){0.f, 0.f, 0.f, 0.f};

    const shortx8* whi8 = (const shortx8*)whi;
    const shortx8* wlo8 = (const shortx8*)wlo;

    for (int kc = 0; kc < 4; ++kc) {
        shortx8 ahi[2], alo[2];
#pragma unroll
        for (int m = 0; m < 2; ++m) {
            int r = rowBase + m * 16 + n16;
            if (r >= N_NODESC) r = N_NODESC - 1;
            if (AFP32) {
                const float* xp = &((const float*)Xv)[(size_t)r * 128 + kc * 32 + q * 8];
                floatx4 x0 = *(const floatx4*)xp;
                floatx4 x1 = *(const floatx4*)(xp + 4);
#pragma unroll
                for (int jj = 0; jj < 4; ++jj) {
                    unsigned short h0 = f32_to_bf16_rne(x0[jj]);
                    ahi[m][jj] = (short)h0;
                    alo[m][jj] = (short)f32_to_bf16_rne(x0[jj] - bf16_to_f32(h0));
                    unsigned short h1 = f32_to_bf16_rne(x1[jj]);
                    ahi[m][jj + 4] = (short)h1;
                    alo[m][jj + 4] = (short)f32_to_bf16_rne(x1[jj] - bf16_to_f32(h1));
                }
            } else {
                const unsigned short* xp = &((const unsigned short*)Xv)[(size_t)r * 128 + kc * 32 + q * 8];
                ahi[m] = *(const shortx8*)xp;
            }
        }
#pragma unroll
        for (int c = 0; c < C; ++c) {
            int fo = (kc * C + c) * 64 + lane;
            shortx8 bhi = whi8[fo];
            shortx8 blo = wlo8[fo];
#pragma unroll
            for (int m = 0; m < 2; ++m) {
                acc[m][c] = __builtin_amdgcn_mfma_f32_16x16x32_bf16(ahi[m], bhi, acc[m][c], 0, 0, 0);
                if (AFP32)
                    acc[m][c] = __builtin_amdgcn_mfma_f32_16x16x32_bf16(alo[m], bhi, acc[m][c], 0, 0, 0);
                acc[m][c] = __builtin_amdgcn_mfma_f32_16x16x32_bf16(ahi[m], blo, acc[m][c], 0, 0, 0);
            }
        }
    }
    // Epilogue: C/D frag (col=c*16+n16, row=q*4+reg) -> LDS -> bf16 rows.
    constexpr int CPL = NOUT / 4;   // cols per lane in readout (4 lanes per row)
#pragma unroll
    for (int m = 0; m < 2; ++m) {
        __syncthreads();
#pragma unroll
        for (int c = 0; c < C; ++c)
#pragma unroll
            for (int reg = 0; reg < 4; ++reg)
                etile[wv][q * 4 + reg][c * 16 + n16] = acc[m][c][reg];
        __syncthreads();
        int row = lane >> 2, cb = lane & 3;
        int r = rowBase + m * 16 + row;
        if (r < N_NODESC) {
            unsigned int po[CPL / 2];
#pragma unroll
            for (int i = 0; i < CPL / 4; ++i) {
                floatx4 v = *(const floatx4*)&etile[wv][row][cb * CPL + i * 4];
                po[i * 2 + 0] = pack2bf(v[0], v[1]);
                po[i * 2 + 1] = pack2bf(v[2], v[3]);
            }
            unsigned int* op = (unsigned int*)&H[(size_t)r * NOUT + cb * CPL];
#pragma unroll
            for (int i = 0; i < CPL / 8; ++i)
                *(uint4*)(op + i * 4) = *(uint4*)&po[i * 4];
        }
    }
}

// ---------------- aggregation d=128 (bf16 in, bf16 out): wave/node, 4 groups of 16
// lanes (16B each), unroll 2 -> 8 gathers in flight. +self+bias+relu ----
__global__ __launch_bounds__(256) void k_agg128(const unsigned short* __restrict__ Hb,
        const int2* __restrict__ sw, const int* __restrict__ row_ptr,
        const int* __restrict__ deg, const float* __restrict__ dinv,
        const float* __restrict__ bias, unsigned short* __restrict__ outb) {
    int node = blockIdx.x * 4 + (threadIdx.x >> 6);
    int lane = threadIdx.x & 63;
    int g = lane >> 4, l16 = lane & 15;
    int start = row_ptr[node];
    int end = start + deg[node];
    float acc[8] = {0.f, 0.f, 0.f, 0.f, 0.f, 0.f, 0.f, 0.f};
    int j = start + g;
    for (; j + 4 < end; j += 8) {
        int2 e0 = sw[j];
        int2 e1 = sw[j + 4];
        uint4 v0 = *(const uint4*)(Hb + (size_t)e0.x * 128 + l16 * 8);
        uint4 v1 = *(const uint4*)(Hb + (size_t)e1.x * 128 + l16 * 8);
        float w0 = __int_as_float(e0.y), w1 = __int_as_float(e1.y);
        acc[0] += bflo(v0.x) * w0 + bflo(v1.x) * w1;
        acc[1] += bfhi(v0.x) * w0 + bfhi(v1.x) * w1;
        acc[2] += bflo(v0.y) * w0 + bflo(v1.y) * w1;
        acc[3] += bfhi(v0.y) * w0 + bfhi(v1.y) * w1;
        acc[4] += bflo(v0.z) * w0 + bflo(v1.z) * w1;
        acc[5] += bfhi(v0.z) * w0 + bfhi(v1.z) * w1;
        acc[6] += bflo(v0.w) * w0 + bflo(v1.w) * w1;
        acc[7] += bfhi(v0.w) * w0 + bfhi(v1.w) * w1;
    }
    if (j < end) {
        int2 e0 = sw[j];
        uint4 v0 = *(const uint4*)(Hb + (size_t)e0.x * 128 + l16 * 8);
        float w0 = __int_as_float(e0.y);
        acc[0] += bflo(v0.x) * w0; acc[1] += bfhi(v0.x) * w0;
        acc[2] += bflo(v0.y) * w0; acc[3] += bfhi(v0.y) * w0;
        acc[4] += bflo(v0.z) * w0; acc[5] += bfhi(v0.z) * w0;
        acc[6] += bflo(v0.w) * w0; acc[7] += bfhi(v0.w) * w0;
    }
#pragma unroll
    for (int i = 0; i < 8; ++i) {
        acc[i] += __shfl_xor(acc[i], 16);
        acc[i] += __shfl_xor(acc[i], 32);
    }
    if (g == 0) {
        float dv = dinv[node];
        float dv2 = dv * dv;
        uint4 sv = *(const uint4*)(Hb + (size_t)node * 128 + l16 * 8);
        floatx4 b0 = *(const floatx4*)&bias[l16 * 8];
        floatx4 b1 = *(const floatx4*)&bias[l16 * 8 + 4];
        acc[0] += bflo(sv.x) * dv2 + b0[0]; acc[1] += bfhi(sv.x) * dv2 + b0[1];
        acc[2] += bflo(sv.y) * dv2 + b0[2]; acc[3] += bfhi(sv.y) * dv2 + b0[3];
        acc[4] += bflo(sv.z) * dv2 + b1[0]; acc[5] += bfhi(sv.z) * dv2 + b1[1];
        acc[6] += bflo(sv.w) * dv2 + b1[2]; acc[7] += bfhi(sv.w) * dv2 + b1[3];
        uint4 o;
        o.x = pack2bf(fmaxf(acc[0], 0.f), fmaxf(acc[1], 0.f));
        o.y = pack2bf(fmaxf(acc[2], 0.f), fmaxf(acc[3], 0.f));
        o.z = pack2bf(fmaxf(acc[4], 0.f), fmaxf(acc[5], 0.f));
        o.w = pack2bf(fmaxf(acc[6], 0.f), fmaxf(acc[7], 0.f));
        *(uint4*)(outb + (size_t)node * 128 + l16 * 8) = o;
    }
}

// ---------------- aggregation d=64 (bf16 in, fp32 out): wave/node, 8 groups of 8
// lanes (16B each), unroll 2 -> 16 gathers in flight. +self+bias, no relu ----
__global__ __launch_bounds__(256) void k_agg64(const unsigned short* __restrict__ Hb,
        const int2* __restrict__ sw, const int* __restrict__ row_ptr,
        const int* __restrict__ deg, const float* __restrict__ dinv,
        const float* __restrict__ bias, float* __restrict__ out) {
    int node = blockIdx.x * 4 + (threadIdx.x >> 6);
    int lane = threadIdx.x & 63;
    int g = lane >> 3, l8 = lane & 7;
    int start = row_ptr[node];
    int end = start + deg[node];
    float acc[8] = {0.f, 0.f, 0.f, 0.f, 0.f, 0.f, 0.f, 0.f};
    int j = start + g;
    for (; j + 8 < end; j += 16) {
        int2 e0 = sw[j];
        int2 e1 = sw[j + 8];
        uint4 v0 = *(const uint4*)(Hb + (size_t)e0.x * 64 + l8 * 8);
        uint4 v1 = *(const uint4*)(Hb + (size_t)e1.x * 64 + l8 * 8);
        float w0 = __int_as_float(e0.y), w1 = __int_as_float(e1.y);
        acc[0] += bflo(v0.x) * w0 + bflo(v1.x) * w1;
        acc[1] += bfhi(v0.x) * w0 + bfhi(v1.x) * w1;
        acc[2] += bflo(v0.y) * w0 + bflo(v1.y) * w1;
        acc[3] += bfhi(v0.y) * w0 + bfhi(v1.y) * w1;
        acc[4] += bflo(v0.z) * w0 + bflo(v1.z) * w1;
        acc[5] += bfhi(v0.z) * w0 + bfhi(v1.z) * w1;
        acc[6] += bflo(v0.w) * w0 + bflo(v1.w) * w1;
        acc[7] += bfhi(v0.w) * w0 + bfhi(v1.w) * w1;
    }
    if (j < end) {
        int2 e0 = sw[j];
        uint4 v0 = *(const uint4*)(Hb + (size_t)e0.x * 64 + l8 * 8);
        float w0 = __int_as_float(e0.y);
        acc[0] += bflo(v0.x) * w0; acc[1] += bfhi(v0.x) * w0;
        acc[2] += bflo(v0.y) * w0; acc[3] += bfhi(v0.y) * w0;
        acc[4] += bflo(v0.z) * w0; acc[5] += bfhi(v0.z) * w0;
        acc[6] += bflo(v0.w) * w0; acc[7] += bfhi(v0.w) * w0;
    }
#pragma unroll
    for (int i = 0; i < 8; ++i) {
        acc[i] += __shfl_xor(acc[i], 8);
        acc[i] += __shfl_xor(acc[i], 16);
        acc[i] += __shfl_xor(acc[i], 32);
    }
    if (g == 0) {
        float dv = dinv[node];
        float dv2 = dv * dv;
        uint4 sv = *(const uint4*)(Hb + (size_t)node * 64 + l8 * 8);
        floatx4 b0 = *(const floatx4*)&bias[l8 * 8];
        floatx4 b1 = *(const floatx4*)&bias[l8 * 8 + 4];
        floatx4 o0, o1;
        o0[0] = acc[0] + bflo(sv.x) * dv2 + b0[0];
        o0[1] = acc[1] + bfhi(sv.x) * dv2 + b0[1];
        o0[2] = acc[2] + bflo(sv.y) * dv2 + b0[2];
        o0[3] = acc[3] + bfhi(sv.y) * dv2 + b0[3];
        o1[0] = acc[4] + bflo(sv.z) * dv2 + b1[0];
        o1[1] = acc[5] + bfhi(sv.z) * dv2 + b1[1];
        o1[2] = acc[6] + bflo(sv.w) * dv2 + b1[2];
        o1[3] = acc[7] + bfhi(sv.w) * dv2 + b1[3];
        *(floatx4*)&out[(size_t)node * 64 + l8 * 8] = o0;
        *(floatx4*)&out[(size_t)node * 64 + l8 * 8 + 4] = o1;
    }
}

extern "C" void kernel_launch(void* const* d_in, const int* in_sizes, int n_in,
                              void* d_out, int out_size, void* d_ws, size_t ws_size,
                              hipStream_t stream) {
    const float* x  = (const float*)d_in[0];
    const int*   ei = (const int*)d_in[1];
    const float* W1 = (const float*)d_in[2];
    const float* b1 = (const float*)d_in[3];
    const float* W2 = (const float*)d_in[4];
    const float* b2 = (const float*)d_in[5];
    float* out = (float*)d_out;
    const int* src = ei;
    const int* dst = ei + N_EDGESC;

    char* ws = (char*)d_ws;
    size_t off = 0;
    auto alloc = [&](size_t bytes) -> void* {
        off = (off + 255) & ~(size_t)255;
        void* p = ws + off;
        off += bytes;
        return p;
    };
    int*   deg     = (int*)  alloc((size_t)N_NODESC * 4);
    float* dinv    = (float*)alloc((size_t)N_NODESC * 4);
    int*   row_ptr = (int*)  alloc((size_t)N_NODESC * 4);
    int*   cursor  = (int*)  alloc((size_t)N_NODESC * 4);
    int*   part    = (int*)  alloc(128 * 4);
    int2*  sw      = (int2*) alloc((size_t)N_EDGESC * 8);
    unsigned short* w1hi = (unsigned short*)alloc(128 * 128 * 2);
    unsigned short* w1lo = (unsigned short*)alloc(128 * 128 * 2);
    unsigned short* w2hi = (unsigned short*)alloc(128 * 64 * 2);
    unsigned short* w2lo = (unsigned short*)alloc(128 * 64 * 2);
    unsigned short* h1b  = (unsigned short*)alloc((size_t)N_NODESC * 128 * 2);
    unsigned short* hb   = (unsigned short*)alloc((size_t)N_NODESC * 128 * 2);
    unsigned short* h2b  = h1b;  // h1b dead after k_agg128; reuse for layer-2 output

    const int nbScan = (N_NODESC + SCAN_CHUNK - 1) / SCAN_CHUNK;  // 98
    const int nbGemm = (N_NODESC + 127) / 128;                    // 782

    hipMemsetAsync(deg, 0, (size_t)N_NODESC * 4, stream);
    k_deg_count<<<N_EDGESC / 256, 256, 0, stream>>>(dst, deg);
    k_dinv<<<(N_NODESC + 255) / 256, 256, 0, stream>>>(deg, dinv);
    k_scan1<<<nbScan, 256, 0, stream>>>(deg, part);
    k_scan2<<<1, 64, 0, stream>>>(part, nbScan);
    k_scan3<<<nbScan, 256, 0, stream>>>(deg, part, row_ptr, cursor);
    k_fill<<<N_EDGESC / 256, 256, 0, stream>>>(src, dst, dinv, cursor, sw);

    k_wfrag<128><<<(128 * 128) / 256, 256, 0, stream>>>(W1, w1hi, w1lo);
    k_wfrag<64><<<(128 * 64) / 256, 256, 0, stream>>>(W2, w2hi, w2lo);

    k_gemm_mfma<128, 1><<<nbGemm, 256, 0, stream>>>(x, w1hi, w1lo, h1b);
    k_agg128<<<N_NODESC / 4, 256, 0, stream>>>(h1b, sw, row_ptr, deg, dinv, b1, hb);
    k_gemm_mfma<64, 0><<<nbGemm, 256, 0, stream>>>(hb, w2hi, w2lo, h2b);
    k_agg64<<<N_NODESC / 4, 256, 0, stream>>>(h2b, sw, row_ptr, deg, dinv, b2, out);
}

// Round 4
// 401.191 us; speedup vs baseline: 1.4103x; 1.0620x over previous
//
#include <hip/hip_runtime.h>

#define N_NODESC 100000
#define N_EDGESC 1600000
#define NB_BUCKETS 391   // ceil(100000/256)
#define CHUNK_A 8192
// IN_C = 128, HID_C = 128, OUT_C = 64

typedef __attribute__((ext_vector_type(4))) float floatx4;
typedef __attribute__((ext_vector_type(8))) short shortx8;

// ---------------- bf16 helpers ----------------
__device__ __forceinline__ unsigned short f32_to_bf16_rne(float f) {
    unsigned int u = __float_as_uint(f);
    unsigned int r = u + 0x7fffu + ((u >> 16) & 1u);
    return (unsigned short)(r >> 16);
}
__device__ __forceinline__ float bf16_to_f32(unsigned short h) {
    return __uint_as_float(((unsigned int)h) << 16);
}
__device__ __forceinline__ float bflo(unsigned int u) { return __uint_as_float(u << 16); }
__device__ __forceinline__ float bfhi(unsigned int u) { return __uint_as_float(u & 0xffff0000u); }
__device__ __forceinline__ unsigned int pack2bf(float a, float b) {
    return ((unsigned int)f32_to_bf16_rne(b) << 16) | (unsigned int)f32_to_bf16_rne(a);
}

// ---------------- degree / dinv ----------------
__global__ void k_deg_count(const int* __restrict__ dst, int* __restrict__ deg) {
    int e = blockIdx.x * blockDim.x + threadIdx.x;
    if (e < N_EDGESC) atomicAdd(&deg[dst[e]], 1);
}

__global__ void k_dinv(const int* __restrict__ deg, float* __restrict__ dinv) {
    int n = blockIdx.x * blockDim.x + threadIdx.x;
    if (n < N_NODESC) dinv[n] = rsqrtf((float)deg[n] + 1.0f);
}

// ---------------- exclusive scan over deg (3 kernels) ----------------
#define SCAN_CHUNK 1024

__global__ void k_scan1(const int* __restrict__ deg, int* __restrict__ part) {
    __shared__ int sdata[256];
    int t = threadIdx.x;
    int base = blockIdx.x * SCAN_CHUNK + t * 4;
    int s = 0;
#pragma unroll
    for (int j = 0; j < 4; ++j) { int i = base + j; if (i < N_NODESC) s += deg[i]; }
    sdata[t] = s;
    __syncthreads();
    for (int off = 128; off > 0; off >>= 1) {
        if (t < off) sdata[t] += sdata[t + off];
        __syncthreads();
    }
    if (t == 0) part[blockIdx.x] = sdata[0];
}

__global__ void k_scan2(int* part, int nb) {
    if (threadIdx.x == 0 && blockIdx.x == 0) {
        int run = 0;
        for (int b = 0; b < nb; ++b) { int v = part[b]; part[b] = run; run += v; }
    }
}

__global__ void k_scan3(const int* __restrict__ deg, const int* __restrict__ part,
                        int* __restrict__ row_ptr, int* __restrict__ cursor) {
    __shared__ int sdata[256];
    int t = threadIdx.x;
    int base = blockIdx.x * SCAN_CHUNK + t * 4;
    int v[4];
    int s = 0;
#pragma unroll
    for (int j = 0; j < 4; ++j) { int i = base + j; v[j] = (i < N_NODESC) ? deg[i] : 0; s += v[j]; }
    sdata[t] = s;
    __syncthreads();
    int own = s;
    for (int off = 1; off < 256; off <<= 1) {
        int add = (t >= off) ? sdata[t - off] : 0;
        __syncthreads();
        sdata[t] += add;
        __syncthreads();
    }
    int excl = sdata[t] - own + part[blockIdx.x];
#pragma unroll
    for (int j = 0; j < 4; ++j) {
        int i = base + j;
        if (i < N_NODESC) { row_ptr[i] = excl; cursor[i] = excl; excl += v[j]; }
    }
}

// ---------------- bucket cursor init: gcur[b] = row_ptr[b*256] ----------------
__global__ void k_binit(const int* __restrict__ row_ptr, int* __restrict__ gcur) {
    int b = blockIdx.x * 256 + threadIdx.x;
    if (b < NB_BUCKETS) gcur[b] = row_ptr[b << 8];
}

// ---------------- phase A: bucket edges by dst>>8 into tmp (packed src<<8 | dlow) --
__global__ __launch_bounds__(256) void k_bucket(const int* __restrict__ src,
        const int* __restrict__ dst, int* __restrict__ gcur,
        unsigned int* __restrict__ tmp) {
    __shared__ int hist[NB_BUCKETS];
    int t = threadIdx.x;
    for (int i = t; i < NB_BUCKETS; i += 256) hist[i] = 0;
    __syncthreads();
    int base = blockIdx.x * CHUNK_A;
    int end = min(base + CHUNK_A, N_EDGESC);
    for (int e = base + t; e < end; e += 256)
        atomicAdd(&hist[dst[e] >> 8], 1);
    __syncthreads();
    for (int i = t; i < NB_BUCKETS; i += 256) {
        int c = hist[i];
        hist[i] = (c > 0) ? atomicAdd(&gcur[i], c) : 0;
    }
    __syncthreads();
    for (int e = base + t; e < end; e += 256) {
        int d = dst[e];
        int pos = atomicAdd(&hist[d >> 8], 1);
        tmp[pos] = ((unsigned int)src[e] << 8) | (unsigned int)(d & 255);
    }
}

// ---------------- phase B: exact CSR placement within L2-resident bucket window --
__global__ __launch_bounds__(256) void k_place(const unsigned int* __restrict__ tmp,
        const int* __restrict__ row_ptr, const int* __restrict__ gcur,
        int* __restrict__ cursor, int* __restrict__ swsrc) {
    int b = blockIdx.x;
    int start = row_ptr[b << 8];
    int end = gcur[b];   // after phase A, gcur[b] == end of bucket b
    int nbase = b << 8;
    for (int i = start + threadIdx.x; i < end; i += 256) {
        unsigned int v = tmp[i];
        int d = nbase + (int)(v & 255u);
        int pos = atomicAdd(&cursor[d], 1);
        swsrc[pos] = (int)(v >> 8);
    }
}

// ---------------- W fragment pre-pack: fp32 [128][NOUT] -> bf16 hi/lo frag order --
template<int NOUT>
__global__ void k_wfrag(const float* __restrict__ W,
                        unsigned short* __restrict__ whi, unsigned short* __restrict__ wlo) {
    int idx = blockIdx.x * 256 + threadIdx.x;    // idx = k*NOUT + col
    constexpr int C = NOUT / 16;
    int k = idx / NOUT, col = idx % NOUT;
    float f = W[idx];
    unsigned short hi = f32_to_bf16_rne(f);
    unsigned short lo = f32_to_bf16_rne(f - bf16_to_f32(hi));
    int kc = k >> 5, q = (k >> 3) & 3, j = k & 7;
    int c = col >> 4, n = col & 15;
    int o = (((kc * C + c) * 4 + q) * 16 + n) * 8 + j;
    whi[o] = hi; wlo[o] = lo;
}

// ---------------- GEMM via MFMA: H[N,NOUT](bf16) = (A[N,128] @ W) * dinv[row] ----
// AFP32=1: A fp32 -> in-register hi/lo split, 3 MFMAs/tile.
// AFP32=0: A bf16 (stored), 2 MFMAs/tile.
// Epilogue: acc -> LDS -> row-scale by dinv -> coalesced bf16 stores.
template<int NOUT, int AFP32>
__global__ __launch_bounds__(256) void k_gemm_mfma(const void* __restrict__ Xv,
        const unsigned short* __restrict__ whi, const unsigned short* __restrict__ wlo,
        const float* __restrict__ dinv, unsigned short* __restrict__ H) {
    constexpr int C = NOUT / 16;
    constexpr int PITCH = NOUT + 4;
    __shared__ __align__(16) float etile[4][16][PITCH];
    int wv = threadIdx.x >> 6, lane = threadIdx.x & 63;
    int n16 = lane & 15, q = lane >> 4;
    int rowBase = blockIdx.x * 128 + wv * 32;
    floatx4 acc[2][C];
#pragma unroll
    for (int m = 0; m < 2; ++m)
#pragma unroll
        for (int c = 0; c < C; ++c) acc[m][c] = (floatx4){0.f, 0.f, 0.f, 0.f};

    const shortx8* whi8 = (const shortx8*)whi;
    const shortx8* wlo8 = (const shortx8*)wlo;

    for (int kc = 0; kc < 4; ++kc) {
        shortx8 ahi[2], alo[2];
#pragma unroll
        for (int m = 0; m < 2; ++m) {
            int r = rowBase + m * 16 + n16;
            if (r >= N_NODESC) r = N_NODESC - 1;
            if (AFP32) {
                const float* xp = &((const float*)Xv)[(size_t)r * 128 + kc * 32 + q * 8];
                floatx4 x0 = *(const floatx4*)xp;
                floatx4 x1 = *(const floatx4*)(xp + 4);
#pragma unroll
                for (int jj = 0; jj < 4; ++jj) {
                    unsigned short h0 = f32_to_bf16_rne(x0[jj]);
                    ahi[m][jj] = (short)h0;
                    alo[m][jj] = (short)f32_to_bf16_rne(x0[jj] - bf16_to_f32(h0));
                    unsigned short h1 = f32_to_bf16_rne(x1[jj]);
                    ahi[m][jj + 4] = (short)h1;
                    alo[m][jj + 4] = (short)f32_to_bf16_rne(x1[jj] - bf16_to_f32(h1));
                }
            } else {
                const unsigned short* xp = &((const unsigned short*)Xv)[(size_t)r * 128 + kc * 32 + q * 8];
                ahi[m] = *(const shortx8*)xp;
            }
        }
#pragma unroll
        for (int c = 0; c < C; ++c) {
            int fo = (kc * C + c) * 64 + lane;
            shortx8 bhi = whi8[fo];
            shortx8 blo = wlo8[fo];
#pragma unroll
            for (int m = 0; m < 2; ++m) {
                acc[m][c] = __builtin_amdgcn_mfma_f32_16x16x32_bf16(ahi[m], bhi, acc[m][c], 0, 0, 0);
                if (AFP32)
                    acc[m][c] = __builtin_amdgcn_mfma_f32_16x16x32_bf16(alo[m], bhi, acc[m][c], 0, 0, 0);
                acc[m][c] = __builtin_amdgcn_mfma_f32_16x16x32_bf16(ahi[m], blo, acc[m][c], 0, 0, 0);
            }
        }
    }
    // Epilogue: C/D frag (col=c*16+n16, row=q*4+reg) -> LDS -> dinv-scaled bf16 rows.
    constexpr int CPL = NOUT / 4;   // cols per lane in readout (4 lanes per row)
#pragma unroll
    for (int m = 0; m < 2; ++m) {
        __syncthreads();
#pragma unroll
        for (int c = 0; c < C; ++c)
#pragma unroll
            for (int reg = 0; reg < 4; ++reg)
                etile[wv][q * 4 + reg][c * 16 + n16] = acc[m][c][reg];
        __syncthreads();
        int row = lane >> 2, cb = lane & 3;
        int r = rowBase + m * 16 + row;
        if (r < N_NODESC) {
            float dv = dinv[r];
            unsigned int po[CPL / 2];
#pragma unroll
            for (int i = 0; i < CPL / 4; ++i) {
                floatx4 v = *(const floatx4*)&etile[wv][row][cb * CPL + i * 4];
                po[i * 2 + 0] = pack2bf(v[0] * dv, v[1] * dv);
                po[i * 2 + 1] = pack2bf(v[2] * dv, v[3] * dv);
            }
            unsigned int* op = (unsigned int*)&H[(size_t)r * NOUT + cb * CPL];
#pragma unroll
            for (int i = 0; i < CPL / 8; ++i)
                *(uint4*)(op + i * 4) = *(uint4*)&po[i * 4];
        }
    }
}

// ---------------- aggregation d=128 (bf16 in/out): out = relu(dinv*(sum h'[s] + h'[n]) + b)
__global__ __launch_bounds__(256) void k_agg128(const unsigned short* __restrict__ Hb,
        const int* __restrict__ swsrc, const int* __restrict__ row_ptr,
        const int* __restrict__ deg, const float* __restrict__ dinv,
        const float* __restrict__ bias, unsigned short* __restrict__ outb) {
    int node = blockIdx.x * 4 + (threadIdx.x >> 6);
    int lane = threadIdx.x & 63;
    int g = lane >> 4, l16 = lane & 15;
    int start = row_ptr[node];
    int end = start + deg[node];
    float acc[8] = {0.f, 0.f, 0.f, 0.f, 0.f, 0.f, 0.f, 0.f};
    int j = start + g;
    for (; j + 4 < end; j += 8) {
        int s0 = swsrc[j];
        int s1 = swsrc[j + 4];
        uint4 v0 = *(const uint4*)(Hb + (size_t)s0 * 128 + l16 * 8);
        uint4 v1 = *(const uint4*)(Hb + (size_t)s1 * 128 + l16 * 8);
        acc[0] += bflo(v0.x) + bflo(v1.x);
        acc[1] += bfhi(v0.x) + bfhi(v1.x);
        acc[2] += bflo(v0.y) + bflo(v1.y);
        acc[3] += bfhi(v0.y) + bfhi(v1.y);
        acc[4] += bflo(v0.z) + bflo(v1.z);
        acc[5] += bfhi(v0.z) + bfhi(v1.z);
        acc[6] += bflo(v0.w) + bflo(v1.w);
        acc[7] += bfhi(v0.w) + bfhi(v1.w);
    }
    if (j < end) {
        int s0 = swsrc[j];
        uint4 v0 = *(const uint4*)(Hb + (size_t)s0 * 128 + l16 * 8);
        acc[0] += bflo(v0.x); acc[1] += bfhi(v0.x);
        acc[2] += bflo(v0.y); acc[3] += bfhi(v0.y);
        acc[4] += bflo(v0.z); acc[5] += bfhi(v0.z);
        acc[6] += bflo(v0.w); acc[7] += bfhi(v0.w);
    }
#pragma unroll
    for (int i = 0; i < 8; ++i) {
        acc[i] += __shfl_xor(acc[i], 16);
        acc[i] += __shfl_xor(acc[i], 32);
    }
    if (g == 0) {
        float dv = dinv[node];
        uint4 sv = *(const uint4*)(Hb + (size_t)node * 128 + l16 * 8);
        floatx4 b0 = *(const floatx4*)&bias[l16 * 8];
        floatx4 b1 = *(const floatx4*)&bias[l16 * 8 + 4];
        float o0 = dv * (acc[0] + bflo(sv.x)) + b0[0];
        float o1 = dv * (acc[1] + bfhi(sv.x)) + b0[1];
        float o2 = dv * (acc[2] + bflo(sv.y)) + b0[2];
        float o3 = dv * (acc[3] + bfhi(sv.y)) + b0[3];
        float o4 = dv * (acc[4] + bflo(sv.z)) + b1[0];
        float o5 = dv * (acc[5] + bfhi(sv.z)) + b1[1];
        float o6 = dv * (acc[6] + bflo(sv.w)) + b1[2];
        float o7 = dv * (acc[7] + bfhi(sv.w)) + b1[3];
        uint4 o;
        o.x = pack2bf(fmaxf(o0, 0.f), fmaxf(o1, 0.f));
        o.y = pack2bf(fmaxf(o2, 0.f), fmaxf(o3, 0.f));
        o.z = pack2bf(fmaxf(o4, 0.f), fmaxf(o5, 0.f));
        o.w = pack2bf(fmaxf(o6, 0.f), fmaxf(o7, 0.f));
        *(uint4*)(outb + (size_t)node * 128 + l16 * 8) = o;
    }
}

// ---------------- aggregation d=64 (bf16 in, fp32 out): out = dinv*(sum + self) + b --
__global__ __launch_bounds__(256) void k_agg64(const unsigned short* __restrict__ Hb,
        const int* __restrict__ swsrc, const int* __restrict__ row_ptr,
        const int* __restrict__ deg, const float* __restrict__ dinv,
        const float* __restrict__ bias, float* __restrict__ out) {
    int node = blockIdx.x * 4 + (threadIdx.x >> 6);
    int lane = threadIdx.x & 63;
    int g = lane >> 3, l8 = lane & 7;
    int start = row_ptr[node];
    int end = start + deg[node];
    float acc[8] = {0.f, 0.f, 0.f, 0.f, 0.f, 0.f, 0.f, 0.f};
    int j = start + g;
    for (; j + 8 < end; j += 16) {
        int s0 = swsrc[j];
        int s1 = swsrc[j + 8];
        uint4 v0 = *(const uint4*)(Hb + (size_t)s0 * 64 + l8 * 8);
        uint4 v1 = *(const uint4*)(Hb + (size_t)s1 * 64 + l8 * 8);
        acc[0] += bflo(v0.x) + bflo(v1.x);
        acc[1] += bfhi(v0.x) + bfhi(v1.x);
        acc[2] += bflo(v0.y) + bflo(v1.y);
        acc[3] += bfhi(v0.y) + bfhi(v1.y);
        acc[4] += bflo(v0.z) + bflo(v1.z);
        acc[5] += bfhi(v0.z) + bfhi(v1.z);
        acc[6] += bflo(v0.w) + bflo(v1.w);
        acc[7] += bfhi(v0.w) + bfhi(v1.w);
    }
    if (j < end) {
        int s0 = swsrc[j];
        uint4 v0 = *(const uint4*)(Hb + (size_t)s0 * 64 + l8 * 8);
        acc[0] += bflo(v0.x); acc[1] += bfhi(v0.x);
        acc[2] += bflo(v0.y); acc[3] += bfhi(v0.y);
        acc[4] += bflo(v0.z); acc[5] += bfhi(v0.z);
        acc[6] += bflo(v0.w); acc[7] += bfhi(v0.w);
    }
#pragma unroll
    for (int i = 0; i < 8; ++i) {
        acc[i] += __shfl_xor(acc[i], 8);
        acc[i] += __shfl_xor(acc[i], 16);
        acc[i] += __shfl_xor(acc[i], 32);
    }
    if (g == 0) {
        float dv = dinv[node];
        uint4 sv = *(const uint4*)(Hb + (size_t)node * 64 + l8 * 8);
        floatx4 b0 = *(const floatx4*)&bias[l8 * 8];
        floatx4 b1 = *(const floatx4*)&bias[l8 * 8 + 4];
        floatx4 o0, o1;
        o0[0] = dv * (acc[0] + bflo(sv.x)) + b0[0];
        o0[1] = dv * (acc[1] + bfhi(sv.x)) + b0[1];
        o0[2] = dv * (acc[2] + bflo(sv.y)) + b0[2];
        o0[3] = dv * (acc[3] + bfhi(sv.y)) + b0[3];
        o1[0] = dv * (acc[4] + bflo(sv.z)) + b1[0];
        o1[1] = dv * (acc[5] + bfhi(sv.z)) + b1[1];
        o1[2] = dv * (acc[6] + bflo(sv.w)) + b1[2];
        o1[3] = dv * (acc[7] + bfhi(sv.w)) + b1[3];
        *(floatx4*)&out[(size_t)node * 64 + l8 * 8] = o0;
        *(floatx4*)&out[(size_t)node * 64 + l8 * 8 + 4] = o1;
    }
}

extern "C" void kernel_launch(void* const* d_in, const int* in_sizes, int n_in,
                              void* d_out, int out_size, void* d_ws, size_t ws_size,
                              hipStream_t stream) {
    const float* x  = (const float*)d_in[0];
    const int*   ei = (const int*)d_in[1];
    const float* W1 = (const float*)d_in[2];
    const float* b1 = (const float*)d_in[3];
    const float* W2 = (const float*)d_in[4];
    const float* b2 = (const float*)d_in[5];
    float* out = (float*)d_out;
    const int* src = ei;
    const int* dst = ei + N_EDGESC;

    char* ws = (char*)d_ws;
    size_t off = 0;
    auto alloc = [&](size_t bytes) -> void* {
        off = (off + 255) & ~(size_t)255;
        void* p = ws + off;
        off += bytes;
        return p;
    };
    int*   deg     = (int*)  alloc((size_t)N_NODESC * 4);
    float* dinv    = (float*)alloc((size_t)N_NODESC * 4);
    int*   row_ptr = (int*)  alloc((size_t)N_NODESC * 4);
    int*   cursor  = (int*)  alloc((size_t)N_NODESC * 4);
    int*   part    = (int*)  alloc(128 * 4);
    int*   gcur    = (int*)  alloc(NB_BUCKETS * 4);
    unsigned int* tmp   = (unsigned int*)alloc((size_t)N_EDGESC * 4);
    int*   swsrc   = (int*)  alloc((size_t)N_EDGESC * 4);
    unsigned short* w1hi = (unsigned short*)alloc(128 * 128 * 2);
    unsigned short* w1lo = (unsigned short*)alloc(128 * 128 * 2);
    unsigned short* w2hi = (unsigned short*)alloc(128 * 64 * 2);
    unsigned short* w2lo = (unsigned short*)alloc(128 * 64 * 2);
    unsigned short* h1b  = (unsigned short*)alloc((size_t)N_NODESC * 128 * 2);
    unsigned short* hb   = (unsigned short*)alloc((size_t)N_NODESC * 128 * 2);
    unsigned short* h2b  = h1b;  // h1b dead after k_agg128; reuse for layer-2 output

    const int nbScan = (N_NODESC + SCAN_CHUNK - 1) / SCAN_CHUNK;  // 98
    const int nbGemm = (N_NODESC + 127) / 128;                    // 782
    const int nbBkt  = (N_EDGESC + CHUNK_A - 1) / CHUNK_A;        // 196

    hipMemsetAsync(deg, 0, (size_t)N_NODESC * 4, stream);
    k_deg_count<<<N_EDGESC / 256, 256, 0, stream>>>(dst, deg);
    k_dinv<<<(N_NODESC + 255) / 256, 256, 0, stream>>>(deg, dinv);
    k_scan1<<<nbScan, 256, 0, stream>>>(deg, part);
    k_scan2<<<1, 64, 0, stream>>>(part, nbScan);
    k_scan3<<<nbScan, 256, 0, stream>>>(deg, part, row_ptr, cursor);
    k_binit<<<(NB_BUCKETS + 255) / 256, 256, 0, stream>>>(row_ptr, gcur);
    k_bucket<<<nbBkt, 256, 0, stream>>>(src, dst, gcur, tmp);
    k_place<<<NB_BUCKETS, 256, 0, stream>>>(tmp, row_ptr, gcur, cursor, swsrc);

    k_wfrag<128><<<(128 * 128) / 256, 256, 0, stream>>>(W1, w1hi, w1lo);
    k_wfrag<64><<<(128 * 64) / 256, 256, 0, stream>>>(W2, w2hi, w2lo);

    k_gemm_mfma<128, 1><<<nbGemm, 256, 0, stream>>>(x, w1hi, w1lo, dinv, h1b);
    k_agg128<<<N_NODESC / 4, 256, 0, stream>>>(h1b, swsrc, row_ptr, deg, dinv, b1, hb);
    k_gemm_mfma<64, 0><<<nbGemm, 256, 0, stream>>>(hb, w2hi, w2lo, dinv, h2b);
    k_agg64<<<N_NODESC / 4, 256, 0, stream>>>(h2b, swsrc, row_ptr, deg, dinv, b2, out);
}

// Round 5
// 311.084 us; speedup vs baseline: 1.8188x; 1.2897x over previous
//
#include <hip/hip_runtime.h>

#define N_NODESC 100000
#define N_EDGESC 1600000
#define NB_BUCKETS 391   // ceil(100000/256)
#define CHUNK_A 8192
// IN_C = 128, HID_C = 128, OUT_C = 64

typedef __attribute__((ext_vector_type(4))) float floatx4;
typedef __attribute__((ext_vector_type(8))) short shortx8;

// ---------------- bf16 helpers ----------------
__device__ __forceinline__ unsigned short f32_to_bf16_rne(float f) {
    unsigned int u = __float_as_uint(f);
    unsigned int r = u + 0x7fffu + ((u >> 16) & 1u);
    return (unsigned short)(r >> 16);
}
__device__ __forceinline__ float bf16_to_f32(unsigned short h) {
    return __uint_as_float(((unsigned int)h) << 16);
}
__device__ __forceinline__ float bflo(unsigned int u) { return __uint_as_float(u << 16); }
__device__ __forceinline__ float bfhi(unsigned int u) { return __uint_as_float(u & 0xffff0000u); }
__device__ __forceinline__ unsigned int pack2bf(float a, float b) {
    return ((unsigned int)f32_to_bf16_rne(b) << 16) | (unsigned int)f32_to_bf16_rne(a);
}

// ---------------- bucket count: LDS hist over 391 buckets, 77k global atomics total --
__global__ __launch_bounds__(256) void k_bcount(const int* __restrict__ dst,
                                                int* __restrict__ bcnt) {
    __shared__ int hist[NB_BUCKETS];
    int t = threadIdx.x;
    for (int i = t; i < NB_BUCKETS; i += 256) hist[i] = 0;
    __syncthreads();
    int base = blockIdx.x * CHUNK_A;
    int end = min(base + CHUNK_A, N_EDGESC);
    for (int e = base + t; e < end; e += 256)
        atomicAdd(&hist[dst[e] >> 8], 1);
    __syncthreads();
    for (int i = t; i < NB_BUCKETS; i += 256)
        if (hist[i] > 0) atomicAdd(&bcnt[i], hist[i]);
}

// ---------------- bucket scan: 512-thread Hillis-Steele over 391 counts ----------
__global__ __launch_bounds__(512) void k_bscan(const int* __restrict__ bcnt,
                                               int* __restrict__ bstart,
                                               int* __restrict__ gcur) {
    __shared__ int s[512];
    int t = threadIdx.x;
    int v = (t < NB_BUCKETS) ? bcnt[t] : 0;
    s[t] = v;
    __syncthreads();
    int own = v;
    for (int off = 1; off < 512; off <<= 1) {
        int add = (t >= off) ? s[t - off] : 0;
        __syncthreads();
        s[t] += add;
        __syncthreads();
    }
    int excl = s[t] - own;
    if (t < NB_BUCKETS) { bstart[t] = excl; gcur[t] = excl; }
}

// ---------------- phase A: bucket edges by dst>>8 into tmp (packed src<<8 | dlow) --
__global__ __launch_bounds__(256) void k_bucket(const int* __restrict__ src,
        const int* __restrict__ dst, int* __restrict__ gcur,
        unsigned int* __restrict__ tmp) {
    __shared__ int hist[NB_BUCKETS];
    int t = threadIdx.x;
    for (int i = t; i < NB_BUCKETS; i += 256) hist[i] = 0;
    __syncthreads();
    int base = blockIdx.x * CHUNK_A;
    int end = min(base + CHUNK_A, N_EDGESC);
    for (int e = base + t; e < end; e += 256)
        atomicAdd(&hist[dst[e] >> 8], 1);
    __syncthreads();
    for (int i = t; i < NB_BUCKETS; i += 256) {
        int c = hist[i];
        hist[i] = (c > 0) ? atomicAdd(&gcur[i], c) : 0;
    }
    __syncthreads();
    for (int e = base + t; e < end; e += 256) {
        int d = dst[e];
        int pos = atomicAdd(&hist[d >> 8], 1);
        tmp[pos] = ((unsigned int)src[e] << 8) | (unsigned int)(d & 255);
    }
}

// ---------------- phase B: per-bucket deg/row_ptr/dinv + exact CSR placement,
// all cursors/histograms in LDS (zero global atomics) ----------------
__global__ __launch_bounds__(256) void k_place(const unsigned int* __restrict__ tmp,
        const int* __restrict__ bstart, const int* __restrict__ gcur,
        int* __restrict__ swsrc, int* __restrict__ deg,
        int* __restrict__ row_ptr, float* __restrict__ dinv) {
    __shared__ int hist[256], scan[256], lcur[256];
    int b = blockIdx.x, t = threadIdx.x;
    int start = bstart[b];
    int end = gcur[b];   // after phase A, gcur[b] == end of bucket b
    hist[t] = 0;
    __syncthreads();
    for (int i = start + t; i < end; i += 256)
        atomicAdd(&hist[tmp[i] & 255u], 1);
    __syncthreads();
    int own = hist[t];
    scan[t] = own;
    __syncthreads();
    for (int off = 1; off < 256; off <<= 1) {
        int add = (t >= off) ? scan[t - off] : 0;
        __syncthreads();
        scan[t] += add;
        __syncthreads();
    }
    int rp = start + scan[t] - own;
    lcur[t] = rp;
    int node = (b << 8) + t;
    if (node < N_NODESC) {
        deg[node] = own;
        row_ptr[node] = rp;
        dinv[node] = rsqrtf((float)own + 1.0f);
    }
    __syncthreads();
    for (int i = start + t; i < end; i += 256) {
        unsigned int v = tmp[i];
        int pos = atomicAdd(&lcur[v & 255u], 1);
        swsrc[pos] = (int)(v >> 8);
    }
}

// ---------------- W fragment pre-pack: fp32 [128][NOUT] -> bf16 hi/lo frag order --
template<int NOUT>
__global__ void k_wfrag(const float* __restrict__ W,
                        unsigned short* __restrict__ whi, unsigned short* __restrict__ wlo) {
    int idx = blockIdx.x * 256 + threadIdx.x;    // idx = k*NOUT + col
    constexpr int C = NOUT / 16;
    int k = idx / NOUT, col = idx % NOUT;
    float f = W[idx];
    unsigned short hi = f32_to_bf16_rne(f);
    unsigned short lo = f32_to_bf16_rne(f - bf16_to_f32(hi));
    int kc = k >> 5, q = (k >> 3) & 3, j = k & 7;
    int c = col >> 4, n = col & 15;
    int o = (((kc * C + c) * 4 + q) * 16 + n) * 8 + j;
    whi[o] = hi; wlo[o] = lo;
}

// ---------------- GEMM via MFMA: H[N,NOUT](bf16) = (A[N,128] @ W) * dinv[row] ----
// AFP32=1: A fp32 -> in-register hi/lo split, 3 MFMAs/tile.
// AFP32=0: A bf16 (stored), 2 MFMAs/tile.
// Epilogue: acc -> LDS -> row-scale by dinv -> coalesced bf16 stores.
template<int NOUT, int AFP32>
__global__ __launch_bounds__(256) void k_gemm_mfma(const void* __restrict__ Xv,
        const unsigned short* __restrict__ whi, const unsigned short* __restrict__ wlo,
        const float* __restrict__ dinv, unsigned short* __restrict__ H) {
    constexpr int C = NOUT / 16;
    constexpr int PITCH = NOUT + 4;
    __shared__ __align__(16) float etile[4][16][PITCH];
    int wv = threadIdx.x >> 6, lane = threadIdx.x & 63;
    int n16 = lane & 15, q = lane >> 4;
    int rowBase = blockIdx.x * 128 + wv * 32;
    floatx4 acc[2][C];
#pragma unroll
    for (int m = 0; m < 2; ++m)
#pragma unroll
        for (int c = 0; c < C; ++c) acc[m][c] = (floatx4){0.f, 0.f, 0.f, 0.f};

    const shortx8* whi8 = (const shortx8*)whi;
    const shortx8* wlo8 = (const shortx8*)wlo;

    for (int kc = 0; kc < 4; ++kc) {
        shortx8 ahi[2], alo[2];
#pragma unroll
        for (int m = 0; m < 2; ++m) {
            int r = rowBase + m * 16 + n16;
            if (r >= N_NODESC) r = N_NODESC - 1;
            if (AFP32) {
                const float* xp = &((const float*)Xv)[(size_t)r * 128 + kc * 32 + q * 8];
                floatx4 x0 = *(const floatx4*)xp;
                floatx4 x1 = *(const floatx4*)(xp + 4);
#pragma unroll
                for (int jj = 0; jj < 4; ++jj) {
                    unsigned short h0 = f32_to_bf16_rne(x0[jj]);
                    ahi[m][jj] = (short)h0;
                    alo[m][jj] = (short)f32_to_bf16_rne(x0[jj] - bf16_to_f32(h0));
                    unsigned short h1 = f32_to_bf16_rne(x1[jj]);
                    ahi[m][jj + 4] = (short)h1;
                    alo[m][jj + 4] = (short)f32_to_bf16_rne(x1[jj] - bf16_to_f32(h1));
                }
            } else {
                const unsigned short* xp = &((const unsigned short*)Xv)[(size_t)r * 128 + kc * 32 + q * 8];
                ahi[m] = *(const shortx8*)xp;
            }
        }
#pragma unroll
        for (int c = 0; c < C; ++c) {
            int fo = (kc * C + c) * 64 + lane;
            shortx8 bhi = whi8[fo];
            shortx8 blo = wlo8[fo];
#pragma unroll
            for (int m = 0; m < 2; ++m) {
                acc[m][c] = __builtin_amdgcn_mfma_f32_16x16x32_bf16(ahi[m], bhi, acc[m][c], 0, 0, 0);
                if (AFP32)
                    acc[m][c] = __builtin_amdgcn_mfma_f32_16x16x32_bf16(alo[m], bhi, acc[m][c], 0, 0, 0);
                acc[m][c] = __builtin_amdgcn_mfma_f32_16x16x32_bf16(ahi[m], blo, acc[m][c], 0, 0, 0);
            }
        }
    }
    // Epilogue: C/D frag (col=c*16+n16, row=q*4+reg) -> LDS -> dinv-scaled bf16 rows.
    constexpr int CPL = NOUT / 4;   // cols per lane in readout (4 lanes per row)
#pragma unroll
    for (int m = 0; m < 2; ++m) {
        __syncthreads();
#pragma unroll
        for (int c = 0; c < C; ++c)
#pragma unroll
            for (int reg = 0; reg < 4; ++reg)
                etile[wv][q * 4 + reg][c * 16 + n16] = acc[m][c][reg];
        __syncthreads();
        int row = lane >> 2, cb = lane & 3;
        int r = rowBase + m * 16 + row;
        if (r < N_NODESC) {
            float dv = dinv[r];
            unsigned int po[CPL / 2];
#pragma unroll
            for (int i = 0; i < CPL / 4; ++i) {
                floatx4 v = *(const floatx4*)&etile[wv][row][cb * CPL + i * 4];
                po[i * 2 + 0] = pack2bf(v[0] * dv, v[1] * dv);
                po[i * 2 + 1] = pack2bf(v[2] * dv, v[3] * dv);
            }
            unsigned int* op = (unsigned int*)&H[(size_t)r * NOUT + cb * CPL];
#pragma unroll
            for (int i = 0; i < CPL / 8; ++i)
                *(uint4*)(op + i * 4) = *(uint4*)&po[i * 4];
        }
    }
}

// ---------------- aggregation d=128 (bf16 in/out): out = relu(dinv*(sum h'[s] + h'[n]) + b)
__global__ __launch_bounds__(256) void k_agg128(const unsigned short* __restrict__ Hb,
        const int* __restrict__ swsrc, const int* __restrict__ row_ptr,
        const int* __restrict__ deg, const float* __restrict__ dinv,
        const float* __restrict__ bias, unsigned short* __restrict__ outb) {
    int node = blockIdx.x * 4 + (threadIdx.x >> 6);
    int lane = threadIdx.x & 63;
    int g = lane >> 4, l16 = lane & 15;
    int start = row_ptr[node];
    int end = start + deg[node];
    float acc[8] = {0.f, 0.f, 0.f, 0.f, 0.f, 0.f, 0.f, 0.f};
    int j = start + g;
    for (; j + 4 < end; j += 8) {
        int s0 = swsrc[j];
        int s1 = swsrc[j + 4];
        uint4 v0 = *(const uint4*)(Hb + (size_t)s0 * 128 + l16 * 8);
        uint4 v1 = *(const uint4*)(Hb + (size_t)s1 * 128 + l16 * 8);
        acc[0] += bflo(v0.x) + bflo(v1.x);
        acc[1] += bfhi(v0.x) + bfhi(v1.x);
        acc[2] += bflo(v0.y) + bflo(v1.y);
        acc[3] += bfhi(v0.y) + bfhi(v1.y);
        acc[4] += bflo(v0.z) + bflo(v1.z);
        acc[5] += bfhi(v0.z) + bfhi(v1.z);
        acc[6] += bflo(v0.w) + bflo(v1.w);
        acc[7] += bfhi(v0.w) + bfhi(v1.w);
    }
    if (j < end) {
        int s0 = swsrc[j];
        uint4 v0 = *(const uint4*)(Hb + (size_t)s0 * 128 + l16 * 8);
        acc[0] += bflo(v0.x); acc[1] += bfhi(v0.x);
        acc[2] += bflo(v0.y); acc[3] += bfhi(v0.y);
        acc[4] += bflo(v0.z); acc[5] += bfhi(v0.z);
        acc[6] += bflo(v0.w); acc[7] += bfhi(v0.w);
    }
#pragma unroll
    for (int i = 0; i < 8; ++i) {
        acc[i] += __shfl_xor(acc[i], 16);
        acc[i] += __shfl_xor(acc[i], 32);
    }
    if (g == 0) {
        float dv = dinv[node];
        uint4 sv = *(const uint4*)(Hb + (size_t)node * 128 + l16 * 8);
        floatx4 b0 = *(const floatx4*)&bias[l16 * 8];
        floatx4 b1 = *(const floatx4*)&bias[l16 * 8 + 4];
        float o0 = dv * (acc[0] + bflo(sv.x)) + b0[0];
        float o1 = dv * (acc[1] + bfhi(sv.x)) + b0[1];
        float o2 = dv * (acc[2] + bflo(sv.y)) + b0[2];
        float o3 = dv * (acc[3] + bfhi(sv.y)) + b0[3];
        float o4 = dv * (acc[4] + bflo(sv.z)) + b1[0];
        float o5 = dv * (acc[5] + bfhi(sv.z)) + b1[1];
        float o6 = dv * (acc[6] + bflo(sv.w)) + b1[2];
        float o7 = dv * (acc[7] + bfhi(sv.w)) + b1[3];
        uint4 o;
        o.x = pack2bf(fmaxf(o0, 0.f), fmaxf(o1, 0.f));
        o.y = pack2bf(fmaxf(o2, 0.f), fmaxf(o3, 0.f));
        o.z = pack2bf(fmaxf(o4, 0.f), fmaxf(o5, 0.f));
        o.w = pack2bf(fmaxf(o6, 0.f), fmaxf(o7, 0.f));
        *(uint4*)(outb + (size_t)node * 128 + l16 * 8) = o;
    }
}

// ---------------- aggregation d=64 (bf16 in, fp32 out): out = dinv*(sum + self) + b --
__global__ __launch_bounds__(256) void k_agg64(const unsigned short* __restrict__ Hb,
        const int* __restrict__ swsrc, const int* __restrict__ row_ptr,
        const int* __restrict__ deg, const float* __restrict__ dinv,
        const float* __restrict__ bias, float* __restrict__ out) {
    int node = blockIdx.x * 4 + (threadIdx.x >> 6);
    int lane = threadIdx.x & 63;
    int g = lane >> 3, l8 = lane & 7;
    int start = row_ptr[node];
    int end = start + deg[node];
    float acc[8] = {0.f, 0.f, 0.f, 0.f, 0.f, 0.f, 0.f, 0.f};
    int j = start + g;
    for (; j + 8 < end; j += 16) {
        int s0 = swsrc[j];
        int s1 = swsrc[j + 8];
        uint4 v0 = *(const uint4*)(Hb + (size_t)s0 * 64 + l8 * 8);
        uint4 v1 = *(const uint4*)(Hb + (size_t)s1 * 64 + l8 * 8);
        acc[0] += bflo(v0.x) + bflo(v1.x);
        acc[1] += bfhi(v0.x) + bfhi(v1.x);
        acc[2] += bflo(v0.y) + bflo(v1.y);
        acc[3] += bfhi(v0.y) + bfhi(v1.y);
        acc[4] += bflo(v0.z) + bflo(v1.z);
        acc[5] += bfhi(v0.z) + bfhi(v1.z);
        acc[6] += bflo(v0.w) + bflo(v1.w);
        acc[7] += bfhi(v0.w) + bfhi(v1.w);
    }
    if (j < end) {
        int s0 = swsrc[j];
        uint4 v0 = *(const uint4*)(Hb + (size_t)s0 * 64 + l8 * 8);
        acc[0] += bflo(v0.x); acc[1] += bfhi(v0.x);
        acc[2] += bflo(v0.y); acc[3] += bfhi(v0.y);
        acc[4] += bflo(v0.z); acc[5] += bfhi(v0.z);
        acc[6] += bflo(v0.w); acc[7] += bfhi(v0.w);
    }
#pragma unroll
    for (int i = 0; i < 8; ++i) {
        acc[i] += __shfl_xor(acc[i], 8);
        acc[i] += __shfl_xor(acc[i], 16);
        acc[i] += __shfl_xor(acc[i], 32);
    }
    if (g == 0) {
        float dv = dinv[node];
        uint4 sv = *(const uint4*)(Hb + (size_t)node * 64 + l8 * 8);
        floatx4 b0 = *(const floatx4*)&bias[l8 * 8];
        floatx4 b1 = *(const floatx4*)&bias[l8 * 8 + 4];
        floatx4 o0, o1;
        o0[0] = dv * (acc[0] + bflo(sv.x)) + b0[0];
        o0[1] = dv * (acc[1] + bfhi(sv.x)) + b0[1];
        o0[2] = dv * (acc[2] + bflo(sv.y)) + b0[2];
        o0[3] = dv * (acc[3] + bfhi(sv.y)) + b0[3];
        o1[0] = dv * (acc[4] + bflo(sv.z)) + b1[0];
        o1[1] = dv * (acc[5] + bfhi(sv.z)) + b1[1];
        o1[2] = dv * (acc[6] + bflo(sv.w)) + b1[2];
        o1[3] = dv * (acc[7] + bfhi(sv.w)) + b1[3];
        *(floatx4*)&out[(size_t)node * 64 + l8 * 8] = o0;
        *(floatx4*)&out[(size_t)node * 64 + l8 * 8 + 4] = o1;
    }
}

extern "C" void kernel_launch(void* const* d_in, const int* in_sizes, int n_in,
                              void* d_out, int out_size, void* d_ws, size_t ws_size,
                              hipStream_t stream) {
    const float* x  = (const float*)d_in[0];
    const int*   ei = (const int*)d_in[1];
    const float* W1 = (const float*)d_in[2];
    const float* b1 = (const float*)d_in[3];
    const float* W2 = (const float*)d_in[4];
    const float* b2 = (const float*)d_in[5];
    float* out = (float*)d_out;
    const int* src = ei;
    const int* dst = ei + N_EDGESC;

    char* ws = (char*)d_ws;
    size_t off = 0;
    auto alloc = [&](size_t bytes) -> void* {
        off = (off + 255) & ~(size_t)255;
        void* p = ws + off;
        off += bytes;
        return p;
    };
    int*   deg     = (int*)  alloc((size_t)N_NODESC * 4);
    float* dinv    = (float*)alloc((size_t)N_NODESC * 4);
    int*   row_ptr = (int*)  alloc((size_t)N_NODESC * 4);
    int*   bcnt    = (int*)  alloc(NB_BUCKETS * 4);
    int*   bstart  = (int*)  alloc(NB_BUCKETS * 4);
    int*   gcur    = (int*)  alloc(NB_BUCKETS * 4);
    unsigned int* tmp   = (unsigned int*)alloc((size_t)N_EDGESC * 4);
    int*   swsrc   = (int*)  alloc((size_t)N_EDGESC * 4);
    unsigned short* w1hi = (unsigned short*)alloc(128 * 128 * 2);
    unsigned short* w1lo = (unsigned short*)alloc(128 * 128 * 2);
    unsigned short* w2hi = (unsigned short*)alloc(128 * 64 * 2);
    unsigned short* w2lo = (unsigned short*)alloc(128 * 64 * 2);
    unsigned short* h1b  = (unsigned short*)alloc((size_t)N_NODESC * 128 * 2);
    unsigned short* hb   = (unsigned short*)alloc((size_t)N_NODESC * 128 * 2);
    unsigned short* h2b  = h1b;  // h1b dead after k_agg128; reuse for layer-2 output

    const int nbGemm = (N_NODESC + 127) / 128;              // 782
    const int nbBkt  = (N_EDGESC + CHUNK_A - 1) / CHUNK_A;  // 196

    hipMemsetAsync(bcnt, 0, NB_BUCKETS * 4, stream);
    k_bcount<<<nbBkt, 256, 0, stream>>>(dst, bcnt);
    k_bscan<<<1, 512, 0, stream>>>(bcnt, bstart, gcur);
    k_bucket<<<nbBkt, 256, 0, stream>>>(src, dst, gcur, tmp);
    k_place<<<NB_BUCKETS, 256, 0, stream>>>(tmp, bstart, gcur, swsrc, deg, row_ptr, dinv);

    k_wfrag<128><<<(128 * 128) / 256, 256, 0, stream>>>(W1, w1hi, w1lo);
    k_wfrag<64><<<(128 * 64) / 256, 256, 0, stream>>>(W2, w2hi, w2lo);

    k_gemm_mfma<128, 1><<<nbGemm, 256, 0, stream>>>(x, w1hi, w1lo, dinv, h1b);
    k_agg128<<<N_NODESC / 4, 256, 0, stream>>>(h1b, swsrc, row_ptr, deg, dinv, b1, hb);
    k_gemm_mfma<64, 0><<<nbGemm, 256, 0, stream>>>(hb, w2hi, w2lo, dinv, h2b);
    k_agg64<<<N_NODESC / 4, 256, 0, stream>>>(h2b, swsrc, row_ptr, deg, dinv, b2, out);
}